// Round 1
// baseline (41.924 us; speedup 1.0000x reference)
//
#include <hip/hip_runtime.h>

// Problem constants (fixed by the reference: X,Y are [32,3,512,512] f32,
// reinterpreted flat as NHWC [32][512][512][3]).
constexpr int Bn     = 32;
constexpr int Wd     = 512;
constexpr int Hd     = 512;
constexpr int Cd     = 3;
constexpr int CROPc  = 5;
constexpr int NOUTc  = Wd - 2 * CROPc;            // 502 outputs per spatial dim
constexpr int HCc    = NOUTc * Cd;                // 1506 (h,c) columns
constexpr int NCHUNK = 8;                         // split w-range for parallelism
constexpr int CHUNKc = (NOUTc + NCHUNK - 1) / NCHUNK; // 63
constexpr int BLOCK  = 256;
constexpr int TOTAL  = Bn * NCHUNK * HCc;         // 385536
constexpr int NBLK   = TOTAL / BLOCK;             // 1506 (exact)
static_assert(TOTAL % BLOCK == 0, "grid must be exact");

// loss = sum_b mean_{w,h,c in crop} [ filt(d^2) - filt(d)^2 ],  d = X - Y
// filt = separable 3x3 gaussian, sigma=1.5:  g = [g0, g1, g0]

__global__ __launch_bounds__(BLOCK) void locvar_kernel(
    const float* __restrict__ X,
    const float* __restrict__ Y,
    float* __restrict__ partial)
{
    const int tid   = blockIdx.x * BLOCK + threadIdx.x;
    const int hcidx = tid % HCc;          // consecutive lanes -> consecutive memory
    const int outer = tid / HCc;
    const int chunk = outer % NCHUNK;
    const int b     = outer / NCHUNK;

    const int h  = CROPc + hcidx / Cd;    // 5..506
    const int c  = hcidx % Cd;
    const int w0 = CROPc + chunk * CHUNKc;
    const int wn = min(CHUNKc, CROPc + NOUTc - w0);  // 63 or 61 (last chunk)

    // gaussian weights (sigma=1.5, ksize=3), computed once per thread (cheap)
    const float e  = expf(-1.0f / 4.5f);
    const float g1 = 1.0f / (1.0f + 2.0f * e);
    const float g0 = e * g1;

    const size_t rowstride = (size_t)Hd * Cd;                  // 1536
    const size_t base = (size_t)b * Wd * rowstride + (size_t)h * Cd + c;

    // Row sums R (filt along h of d) and Q (filt along h of d^2) for w-1, w
    float R0, R1, Q0, Q1;
    {
        size_t off = base + (size_t)(w0 - 1) * rowstride;
        float dm = X[off - 3] - Y[off - 3];
        float d0 = X[off]     - Y[off];
        float dp = X[off + 3] - Y[off + 3];
        R0 = g0 * (dm + dp) + g1 * d0;
        Q0 = g0 * (dm * dm + dp * dp) + g1 * (d0 * d0);
    }
    {
        size_t off = base + (size_t)w0 * rowstride;
        float dm = X[off - 3] - Y[off - 3];
        float d0 = X[off]     - Y[off];
        float dp = X[off + 3] - Y[off + 3];
        R1 = g0 * (dm + dp) + g1 * d0;
        Q1 = g0 * (dm * dm + dp * dp) + g1 * (d0 * d0);
    }

    float acc = 0.0f;
    size_t off = base + (size_t)(w0 + 1) * rowstride;
    for (int i = 0; i < wn; ++i, off += rowstride) {
        float dm = X[off - 3] - Y[off - 3];
        float d0 = X[off]     - Y[off];
        float dp = X[off + 3] - Y[off + 3];
        float R2 = g0 * (dm + dp) + g1 * d0;
        float Q2 = g0 * (dm * dm + dp * dp) + g1 * (d0 * d0);

        float S1 = g0 * (R0 + R2) + g1 * R1;   // filt(d)  at (w,h,c)
        float S2 = g0 * (Q0 + Q2) + g1 * Q1;   // filt(d^2)
        acc += S2 - S1 * S1;

        R0 = R1; R1 = R2;
        Q0 = Q1; Q1 = Q2;
    }

    // deterministic block reduction: wave shuffle then LDS
    #pragma unroll
    for (int o = 32; o > 0; o >>= 1) acc += __shfl_down(acc, o, 64);

    __shared__ float sdata[BLOCK / 64];
    const int lane = threadIdx.x & 63;
    const int wid  = threadIdx.x >> 6;
    if (lane == 0) sdata[wid] = acc;
    __syncthreads();
    if (threadIdx.x == 0) {
        float s = 0.0f;
        #pragma unroll
        for (int i = 0; i < BLOCK / 64; ++i) s += sdata[i];
        partial[blockIdx.x] = s;
    }
}

__global__ __launch_bounds__(BLOCK) void reduce_kernel(
    const float* __restrict__ partial,
    float* __restrict__ out)
{
    float acc = 0.0f;
    for (int i = threadIdx.x; i < NBLK; i += BLOCK) acc += partial[i];

    #pragma unroll
    for (int o = 32; o > 0; o >>= 1) acc += __shfl_down(acc, o, 64);

    __shared__ float sdata[BLOCK / 64];
    const int lane = threadIdx.x & 63;
    const int wid  = threadIdx.x >> 6;
    if (lane == 0) sdata[wid] = acc;
    __syncthreads();
    if (threadIdx.x == 0) {
        float s = 0.0f;
        #pragma unroll
        for (int i = 0; i < BLOCK / 64; ++i) s += sdata[i];
        // sum over batch of per-batch mean = total / (502*502*3)
        out[0] = s * (1.0f / ((float)NOUTc * (float)NOUTc * (float)Cd));
    }
}

extern "C" void kernel_launch(void* const* d_in, const int* in_sizes, int n_in,
                              void* d_out, int out_size, void* d_ws, size_t ws_size,
                              hipStream_t stream) {
    const float* X = (const float*)d_in[0];
    const float* Y = (const float*)d_in[1];
    float* out     = (float*)d_out;
    float* partial = (float*)d_ws;   // NBLK floats = ~6 KB scratch

    locvar_kernel<<<NBLK, BLOCK, 0, stream>>>(X, Y, partial);
    reduce_kernel<<<1, BLOCK, 0, stream>>>(partial, out);
}